// Round 18
// baseline (190.146 us; speedup 1.0000x reference)
//
#include <hip/hip_runtime.h>

#define LEAKY_SLOPE 0.2f

constexpr int B_   = 16;
constexpr int N_   = 4096;
constexpr int K_   = 4096;
constexpr int IN_  = 16384;   // K + 3K
constexpr int H1_  = 1024;
constexpr int H2_  = 512;
constexpr int OUT_ = 256;

// encode tiling: 64 n-chunks x 64 points (1KB LDS), 8 k per thread
constexpr int NCH = 64;
constexpr int NPC = N_ / NCH;   // 64
constexpr int KPT = 8;
constexpr int KTB = 256 * KPT;  // 2048 k per block -> grid.x = 2

// gemm1 chunking (validated r13): 1024 blocks, 4/CU
constexpr int GCH = 128;

// -------------------------------------------------------------------------
// Phase 1: per-chunk MIN-ONLY.  r14: process points in PAIRS with
// fmin(best, fmin(ea,eb)) -> v_min3_f32 -> 3.5 VALU/pair (was 4).
// fmin is associative/commutative on finite values -> bit-identical min.
// Validated structure r10/r13.
// -------------------------------------------------------------------------
__global__ __launch_bounds__(256) void enc_partial(
    const float* __restrict__ pc, const float* __restrict__ basis,
    float* __restrict__ chunkminf)
{
#pragma clang fp contract(off)
    __shared__ float4 pts[NPC + 2];     // +2 sentinels for pair-prefetch
    const int kt = blockIdx.x;
    const int b  = blockIdx.y;
    const int c  = blockIdx.z;
    const int n0 = c * NPC;

    if (threadIdx.x < NPC) {
        const float* pp = pc + ((size_t)b * N_ + n0 + threadIdx.x) * 3;
        float x = pp[0], y = pp[1], z = pp[2];
        pts[threadIdx.x] = make_float4(x, y, z, (x * x + y * y) + z * z);
    }
    if (threadIdx.x < 2)
        pts[NPC + threadIdx.x] = make_float4(0.f, 0.f, 0.f, 0.f);
    __syncthreads();

    const int k0 = kt * KTB + (int)threadIdx.x;
    float nbx[KPT], nby[KPT], nbz[KPT], best[KPT];
#pragma unroll
    for (int q = 0; q < KPT; ++q) {
        int k = k0 + q * 256;
        nbx[q] = -2.0f * basis[k * 3 + 0];
        nby[q] = -2.0f * basis[k * 3 + 1];
        nbz[q] = -2.0f * basis[k * 3 + 2];
        best[q] = 3.4028235e38f;
    }

    float4 pa = pts[0];
    float4 pb = pts[1];
#pragma unroll 2
    for (int n = 0; n < NPC; n += 2) {
        float4 pc2 = pts[n + 2];        // prefetch next pair
        float4 pd  = pts[n + 3];
#pragma unroll
        for (int q = 0; q < KPT; ++q) {
            float ea = __builtin_fmaf(nbx[q], pa.x,
                        __builtin_fmaf(nby[q], pa.y,
                         __builtin_fmaf(nbz[q], pa.z, pa.w)));
            float eb = __builtin_fmaf(nbx[q], pb.x,
                        __builtin_fmaf(nby[q], pb.y,
                         __builtin_fmaf(nbz[q], pb.z, pb.w)));
            best[q] = __builtin_fminf(best[q], __builtin_fminf(ea, eb));
        }
        pa = pc2; pb = pd;
    }

    float* dst = chunkminf + ((size_t)(c * B_ + b)) * K_;
#pragma unroll
    for (int q = 0; q < KPT; ++q)
        dst[k0 + q * 256] = best[q];
}

// -------------------------------------------------------------------------
// Phase 2: fold 64 chunk-min floats (strict < keeps FIRST min chunk),
// rescan winning chunk (64 pts, L2-hot), bit-identical e2 chain ->
// exact reference argmin.  Validated r10/r13.
// -------------------------------------------------------------------------
__global__ __launch_bounds__(256) void enc_reduce_finish(
    const float* __restrict__ pc, const float* __restrict__ basis,
    const float* __restrict__ chunkminf,
    float* __restrict__ bps_out)
{
#pragma clang fp contract(off)
    const int t = blockIdx.x * 256 + (int)threadIdx.x;   // 0 .. B*K-1
    const int b = t >> 12;
    const int k = t & (K_ - 1);

    float m = 3.4028235e38f;
    int   cb = 0;
#pragma unroll 8
    for (int c = 0; c < NCH; ++c) {
        float v = chunkminf[((size_t)(c * B_ + b)) * K_ + k];
        if (v < m) { m = v; cb = c; }   // strict < -> first chunk on ties
    }

    const float bx0 = basis[k * 3 + 0];
    const float by0 = basis[k * 3 + 1];
    const float bz0 = basis[k * 3 + 2];
    const float nbx = -2.0f * bx0;
    const float nby = -2.0f * by0;
    const float nbz = -2.0f * bz0;

    // rescan chunk cb: 64 points = 48 float4s, 16B-aligned (768B stride)
    const float4* pch = (const float4*)(pc + ((size_t)b * N_ + cb * NPC) * 3);
    float mm = 3.4028235e38f;
    float px = 0.f, py = 0.f, pz = 0.f;
#pragma unroll 4
    for (int g = 0; g < NPC / 4; ++g) {
        float4 q0 = pch[3 * g + 0];
        float4 q1 = pch[3 * g + 1];
        float4 q2 = pch[3 * g + 2];
        float xs[4] = { q0.x, q0.w, q1.z, q2.y };
        float ys[4] = { q0.y, q1.x, q1.w, q2.z };
        float zs[4] = { q0.z, q1.y, q2.x, q2.w };
#pragma unroll
        for (int j = 0; j < 4; ++j) {
            float x = xs[j], y = ys[j], z = zs[j];
            float pw = (x * x + y * y) + z * z;          // == phase-1 staging
            float e2 = __builtin_fmaf(nbx, x,
                        __builtin_fmaf(nby, y,
                         __builtin_fmaf(nbz, z, pw)));   // == phase-1 chain
            if (e2 < mm) { mm = e2; px = x; py = y; pz = z; }  // first min
        }
    }

    float dx = px - bx0;
    float dy = py - by0;
    float dz = pz - bz0;
    float dist = sqrtf((dx * dx + dy * dy) + dz * dz);

    float* row = bps_out + (size_t)b * IN_;
    row[k]              = dist;
    row[K_ + 3 * k + 0] = dx;
    row[K_ + 3 * k + 1] = dy;
    row[K_ + 3 * k + 2] = dz;
}

// -------------------------------------------------------------------------
// L1 GEMM (validated r13, 167.5): read-W-once, 1024 blocks (4/CU).
// partial layout [chunk][16][H1].
// -------------------------------------------------------------------------
template<int ILEN, int NCOLS>
__global__ __launch_bounds__(256) void gemm1(
    const float* __restrict__ A, const float* __restrict__ W,
    float* __restrict__ part)
{
    __shared__ float red[4][64][33];
    const int lane = (int)threadIdx.x & 63;
    const int w    = __builtin_amdgcn_readfirstlane((int)threadIdx.x >> 6);
    const int j0   = blockIdx.x * 128 + lane * 2;
    const int i0   = blockIdx.y * ILEN + w * (ILEN / 4);

    float2 acc[16];
#pragma unroll
    for (int r = 0; r < 16; ++r) acc[r] = make_float2(0.f, 0.f);

#pragma unroll 4
    for (int i = i0; i < i0 + ILEN / 4; ++i) {
        float2 wv = *(const float2*)(W + (size_t)i * NCOLS + j0);
#pragma unroll
        for (int r = 0; r < 16; ++r) {
            float a = A[(size_t)r * IN_ + i];       // wave-uniform -> s_load
            acc[r].x = __builtin_fmaf(a, wv.x, acc[r].x);
            acc[r].y = __builtin_fmaf(a, wv.y, acc[r].y);
        }
    }

#pragma unroll
    for (int r = 0; r < 16; ++r) {
        red[w][lane][2 * r]     = acc[r].x;
        red[w][lane][2 * r + 1] = acc[r].y;
    }
    __syncthreads();

    // cross-wave fold: thread (w, lane) -> batches [4w, 4w+4) x col pair lane
    float* base = part + (size_t)blockIdx.y * 16 * NCOLS + blockIdx.x * 128 + lane * 2;
    const int b0 = w * 4;
#pragma unroll
    for (int b = b0; b < b0 + 4; ++b) {
        float sx = 0.f, sy = 0.f;
#pragma unroll
        for (int ww = 0; ww < 4; ++ww) {
            sx += red[ww][lane][2 * b];
            sy += red[ww][lane][2 * b + 1];
        }
        *(float2*)(base + (size_t)b * NCOLS) = make_float2(sx, sy);
    }
}

// -------------------------------------------------------------------------
// Reduce 128 chunk-partials + bias + leaky -> h1T[col][16]  (validated r13)
// -------------------------------------------------------------------------
__global__ __launch_bounds__(256) void reduce_act1(
    const float* __restrict__ part, const float* __restrict__ bias,
    float* __restrict__ outT)
{
    const int p = blockIdx.x * 256 + (int)threadIdx.x;   // b*H1 + col
    float s = 0.0f;
#pragma unroll 8
    for (int c = 0; c < GCH; ++c) s += part[(size_t)c * (16 * H1_) + p];
    const int col = p & (H1_ - 1);
    const int b   = p >> 10;
    s += bias[col];
    s = fmaxf(s, LEAKY_SLOPE * s);
    outT[(size_t)col * 16 + b] = s;
}

// -------------------------------------------------------------------------
// L2 GEMM, split-K (validated r4/r10/r13): grid (8 colblocks x 8 kslices).
// part layout: [slice][col][16].  No bias/act (folded into gemm_last).
// -------------------------------------------------------------------------
template<int KDIM, int NCOLS>
__global__ __launch_bounds__(256) void gemm_mid(
    const float* __restrict__ AT, const float* __restrict__ W,
    float* __restrict__ part)
{
    __shared__ float red[4][64][17];
    const int lane = (int)threadIdx.x & 63;
    const int w    = __builtin_amdgcn_readfirstlane((int)threadIdx.x >> 6);
    const int cb   = blockIdx.x;
    const int s    = blockIdx.y;
    const int j    = cb * 64 + lane;
    constexpr int KS = KDIM / 8;    // 128 i per slice
    constexpr int KW = KS / 4;      // 32 i per wave
    const int i0 = s * KS + w * KW;

    float acc[16];
#pragma unroll
    for (int r = 0; r < 16; ++r) acc[r] = 0.0f;

#pragma unroll 4
    for (int i = i0; i < i0 + KW; ++i) {
        float wv = W[(size_t)i * NCOLS + j];
        const float4* Ar = (const float4*)(AT + (size_t)i * 16);
        float4 q0 = Ar[0], q1 = Ar[1], q2 = Ar[2], q3 = Ar[3];
        acc[0]  = __builtin_fmaf(q0.x, wv, acc[0]);
        acc[1]  = __builtin_fmaf(q0.y, wv, acc[1]);
        acc[2]  = __builtin_fmaf(q0.z, wv, acc[2]);
        acc[3]  = __builtin_fmaf(q0.w, wv, acc[3]);
        acc[4]  = __builtin_fmaf(q1.x, wv, acc[4]);
        acc[5]  = __builtin_fmaf(q1.y, wv, acc[5]);
        acc[6]  = __builtin_fmaf(q1.z, wv, acc[6]);
        acc[7]  = __builtin_fmaf(q1.w, wv, acc[7]);
        acc[8]  = __builtin_fmaf(q2.x, wv, acc[8]);
        acc[9]  = __builtin_fmaf(q2.y, wv, acc[9]);
        acc[10] = __builtin_fmaf(q2.z, wv, acc[10]);
        acc[11] = __builtin_fmaf(q2.w, wv, acc[11]);
        acc[12] = __builtin_fmaf(q3.x, wv, acc[12]);
        acc[13] = __builtin_fmaf(q3.y, wv, acc[13]);
        acc[14] = __builtin_fmaf(q3.z, wv, acc[14]);
        acc[15] = __builtin_fmaf(q3.w, wv, acc[15]);
    }

#pragma unroll
    for (int r = 0; r < 16; ++r) red[w][lane][r] = acc[r];
    __syncthreads();

#pragma unroll
    for (int q = 0; q < 4; ++q) {
        int p  = (int)threadIdx.x * 4 + q;   // col_local*16 + batch
        int cl = p >> 4;
        int bt = p & 15;
        float ssum = 0.0f;
#pragma unroll
        for (int ww = 0; ww < 4; ++ww) ssum += red[ww][cl][bt];
        part[((size_t)s * NCOLS + cb * 64 + cl) * 16 + bt] = ssum;
    }
}

// -------------------------------------------------------------------------
// L3 GEMM fused with final fold (r14): grid (4 blocks), each block:
// A-prep ALL 512 i (8-slice fold + b2 + leaky, sl-ascending as before) into
// LDS, full-K MMA for its 64 output cols, + b3, write gfeat directly.
// Removes out_final dispatch + h3part round-trip.
// -------------------------------------------------------------------------
template<int KDIM, int NCOLS>
__global__ __launch_bounds__(256) void gemm_last(
    const float* __restrict__ h2part, const float* __restrict__ b2,
    const float* __restrict__ W, const float* __restrict__ b3,
    float* __restrict__ outp)
{
    __shared__ float aT[KDIM][20];          // 512 x 20 x 4B = 40 KB
    __shared__ float red[4][64][17];        // 17 KB
    const int tid  = (int)threadIdx.x;
    const int lane = tid & 63;
    const int w    = __builtin_amdgcn_readfirstlane(tid >> 6);
    const int cb   = (int)blockIdx.x;

    // A-prep: 2048 float4-items (512 i x 4 quads), 8 per thread
#pragma unroll
    for (int u = 0; u < 8; ++u) {
        const int item = tid * 8 + u;
        const int il   = item >> 2;
        const int btq  = (item & 3) * 4;
        float4 sum = make_float4(0.f, 0.f, 0.f, 0.f);
#pragma unroll
        for (int sl = 0; sl < 8; ++sl) {
            const float4 v = *(const float4*)(h2part +
                ((size_t)sl * H2_ + il) * 16 + btq);
            sum.x += v.x; sum.y += v.y; sum.z += v.z; sum.w += v.w;
        }
        const float bb = b2[il];
        sum.x += bb; sum.y += bb; sum.z += bb; sum.w += bb;
        sum.x = fmaxf(sum.x, LEAKY_SLOPE * sum.x);
        sum.y = fmaxf(sum.y, LEAKY_SLOPE * sum.y);
        sum.z = fmaxf(sum.z, LEAKY_SLOPE * sum.z);
        sum.w = fmaxf(sum.w, LEAKY_SLOPE * sum.w);
        *(float4*)&aT[il][btq] = sum;
    }
    __syncthreads();

    const int j  = cb * 64 + lane;
    const int i0 = w * (KDIM / 4);          // 128 i per wave
    float acc[16];
#pragma unroll
    for (int r = 0; r < 16; ++r) acc[r] = 0.0f;

#pragma unroll 4
    for (int il = i0; il < i0 + KDIM / 4; ++il) {
        float wv = W[(size_t)il * NCOLS + j];
        float4 q0 = *(const float4*)&aT[il][0];
        float4 q1 = *(const float4*)&aT[il][4];
        float4 q2 = *(const float4*)&aT[il][8];
        float4 q3 = *(const float4*)&aT[il][12];
        acc[0]  = __builtin_fmaf(q0.x, wv, acc[0]);
        acc[1]  = __builtin_fmaf(q0.y, wv, acc[1]);
        acc[2]  = __builtin_fmaf(q0.z, wv, acc[2]);
        acc[3]  = __builtin_fmaf(q0.w, wv, acc[3]);
        acc[4]  = __builtin_fmaf(q1.x, wv, acc[4]);
        acc[5]  = __builtin_fmaf(q1.y, wv, acc[5]);
        acc[6]  = __builtin_fmaf(q1.z, wv, acc[6]);
        acc[7]  = __builtin_fmaf(q1.w, wv, acc[7]);
        acc[8]  = __builtin_fmaf(q2.x, wv, acc[8]);
        acc[9]  = __builtin_fmaf(q2.y, wv, acc[9]);
        acc[10] = __builtin_fmaf(q2.z, wv, acc[10]);
        acc[11] = __builtin_fmaf(q2.w, wv, acc[11]);
        acc[12] = __builtin_fmaf(q3.x, wv, acc[12]);
        acc[13] = __builtin_fmaf(q3.y, wv, acc[13]);
        acc[14] = __builtin_fmaf(q3.z, wv, acc[14]);
        acc[15] = __builtin_fmaf(q3.w, wv, acc[15]);
    }

#pragma unroll
    for (int r = 0; r < 16; ++r) red[w][lane][r] = acc[r];
    __syncthreads();

#pragma unroll
    for (int q = 0; q < 4; ++q) {
        int p  = tid * 4 + q;
        int cl = p >> 4;
        int bt = p & 15;
        const int col = cb * 64 + cl;
        float s = b3[col];
#pragma unroll
        for (int ww = 0; ww < 4; ++ww) s += red[ww][cl][bt];
        outp[(size_t)bt * NCOLS + col] = s;
    }
}

// -------------------------------------------------------------------------
extern "C" void kernel_launch(void* const* d_in, const int* in_sizes, int n_in,
                              void* d_out, int out_size, void* d_ws, size_t ws_size,
                              hipStream_t stream)
{
    const float* pc    = (const float*)d_in[0];
    const float* basis = (const float*)d_in[1];
    const float* W1    = (const float*)d_in[2];
    const float* b1    = (const float*)d_in[3];
    const float* W2    = (const float*)d_in[4];
    const float* b2    = (const float*)d_in[5];
    const float* W3    = (const float*)d_in[6];
    const float* b3    = (const float*)d_in[7];

    float* out   = (float*)d_out;
    float* gfeat = out;                 // [16][256]
    float* bps   = out + B_ * OUT_;     // [16][16384]

    char* ws = (char*)d_ws;
    float* chunkminf = (float*)ws;                                   // 16 MB
    float* partial = (float*)(ws + (size_t)16 * 1024 * 1024);        // 8 MB [128][16][H1]
    float* h1T     = (float*)(ws + (size_t)24 * 1024 * 1024);        // 64 KB
    float* h2part  = (float*)(ws + (size_t)24 * 1024 * 1024 + 64 * 1024);   // 256 KB

    // 1) phase-1 min-only per chunk (3.5 VALU/pair via min3 pairing)
    enc_partial<<<dim3(K_ / KTB, B_, NCH), 256, 0, stream>>>(pc, basis, chunkminf);
    // 2) fold 64 chunk-mins + rescan winning chunk + write bps feature
    enc_reduce_finish<<<(B_ * K_) / 256, 256, 0, stream>>>(pc, basis, chunkminf, bps);
    // 3) L1 GEMM [16,16384]@[16384,1024]; 1024 blocks (4/CU)
    gemm1<128, H1_><<<dim3(8, GCH), 256, 0, stream>>>(bps, W1, partial);
    // 4) reduce 128 partials + bias + leaky -> h1T
    reduce_act1<<<(H1_ * 16) / 256, 256, 0, stream>>>(partial, b1, h1T);
    // 5) L2 split-K GEMM [16,1024]@[1024,512] -> h2part[8][512][16]
    gemm_mid<1024, H2_><<<dim3(8, 8), 256, 0, stream>>>(h1T, W2, h2part);
    // 6) L3 GEMM fused with slice-fold + b3 -> gfeat (replaces 2 dispatches)
    gemm_last<512, OUT_><<<4, 256, 0, stream>>>(h2part, b2, W3, b3, gfeat);
}

// Round 22
// 166.020 us; speedup vs baseline: 1.1453x; 1.1453x over previous
//
#include <hip/hip_runtime.h>

#define LEAKY_SLOPE 0.2f

constexpr int B_   = 16;
constexpr int N_   = 4096;
constexpr int K_   = 4096;
constexpr int IN_  = 16384;   // K + 3K
constexpr int H1_  = 1024;
constexpr int H2_  = 512;
constexpr int OUT_ = 256;

// encode tiling: 64 n-chunks x 64 points (1KB LDS), 8 k per thread
constexpr int NCH = 64;
constexpr int NPC = N_ / NCH;   // 64
constexpr int KPT = 8;
constexpr int KTB = 256 * KPT;  // 2048 k per block -> grid.x = 2

// gemm1 chunking (validated r13): 1024 blocks, 4/CU
constexpr int GCH = 128;

// -------------------------------------------------------------------------
// Phase 1: per-chunk MIN-ONLY (no index) -> 4 VALU/pair (3 fma + v_min).
// EXACT r13-measured form (167.5 us).  min3 pairing variant is parked
// unmeasured (r8 precedent: inner-loop micro-opts here can regress).
// Index recovered in phase 2 by rescanning the winning chunk.
// -------------------------------------------------------------------------
__global__ __launch_bounds__(256) void enc_partial(
    const float* __restrict__ pc, const float* __restrict__ basis,
    float* __restrict__ chunkminf)
{
#pragma clang fp contract(off)
    __shared__ float4 pts[NPC + 1];     // +1 sentinel for prefetch overrun
    const int kt = blockIdx.x;
    const int b  = blockIdx.y;
    const int c  = blockIdx.z;
    const int n0 = c * NPC;

    if (threadIdx.x < NPC) {
        const float* pp = pc + ((size_t)b * N_ + n0 + threadIdx.x) * 3;
        float x = pp[0], y = pp[1], z = pp[2];
        pts[threadIdx.x] = make_float4(x, y, z, (x * x + y * y) + z * z);
    }
    if (threadIdx.x == 0) pts[NPC] = make_float4(0.f, 0.f, 0.f, 0.f);
    __syncthreads();

    const int k0 = kt * KTB + (int)threadIdx.x;
    float nbx[KPT], nby[KPT], nbz[KPT], best[KPT];
#pragma unroll
    for (int q = 0; q < KPT; ++q) {
        int k = k0 + q * 256;
        nbx[q] = -2.0f * basis[k * 3 + 0];
        nby[q] = -2.0f * basis[k * 3 + 1];
        nbz[q] = -2.0f * basis[k * 3 + 2];
        best[q] = 3.4028235e38f;
    }

    float4 pcur = pts[0];
#pragma unroll 4
    for (int n = 0; n < NPC; ++n) {
        float4 pnext = pts[n + 1];      // prefetch next point during compute
#pragma unroll
        for (int q = 0; q < KPT; ++q) {
            float e2 = __builtin_fmaf(nbx[q], pcur.x,
                        __builtin_fmaf(nby[q], pcur.y,
                         __builtin_fmaf(nbz[q], pcur.z, pcur.w)));
            best[q] = __builtin_fminf(best[q], e2);
        }
        pcur = pnext;
    }

    float* dst = chunkminf + ((size_t)(c * B_ + b)) * K_;
#pragma unroll
    for (int q = 0; q < KPT; ++q)
        dst[k0 + q * 256] = best[q];
}

// -------------------------------------------------------------------------
// Phase 2: fold 64 chunk-min floats (strict < keeps FIRST min chunk),
// rescan winning chunk (64 pts, L2-hot), bit-identical e2 chain ->
// exact reference argmin.  Validated r10/r13.
// -------------------------------------------------------------------------
__global__ __launch_bounds__(256) void enc_reduce_finish(
    const float* __restrict__ pc, const float* __restrict__ basis,
    const float* __restrict__ chunkminf,
    float* __restrict__ bps_out)
{
#pragma clang fp contract(off)
    const int t = blockIdx.x * 256 + (int)threadIdx.x;   // 0 .. B*K-1
    const int b = t >> 12;
    const int k = t & (K_ - 1);

    float m = 3.4028235e38f;
    int   cb = 0;
#pragma unroll 8
    for (int c = 0; c < NCH; ++c) {
        float v = chunkminf[((size_t)(c * B_ + b)) * K_ + k];
        if (v < m) { m = v; cb = c; }   // strict < -> first chunk on ties
    }

    const float bx0 = basis[k * 3 + 0];
    const float by0 = basis[k * 3 + 1];
    const float bz0 = basis[k * 3 + 2];
    const float nbx = -2.0f * bx0;
    const float nby = -2.0f * by0;
    const float nbz = -2.0f * bz0;

    // rescan chunk cb: 64 points = 48 float4s, 16B-aligned (768B stride)
    const float4* pch = (const float4*)(pc + ((size_t)b * N_ + cb * NPC) * 3);
    float mm = 3.4028235e38f;
    float px = 0.f, py = 0.f, pz = 0.f;
#pragma unroll 4
    for (int g = 0; g < NPC / 4; ++g) {
        float4 q0 = pch[3 * g + 0];
        float4 q1 = pch[3 * g + 1];
        float4 q2 = pch[3 * g + 2];
        float xs[4] = { q0.x, q0.w, q1.z, q2.y };
        float ys[4] = { q0.y, q1.x, q1.w, q2.z };
        float zs[4] = { q0.z, q1.y, q2.x, q2.w };
#pragma unroll
        for (int j = 0; j < 4; ++j) {
            float x = xs[j], y = ys[j], z = zs[j];
            float pw = (x * x + y * y) + z * z;          // == phase-1 staging
            float e2 = __builtin_fmaf(nbx, x,
                        __builtin_fmaf(nby, y,
                         __builtin_fmaf(nbz, z, pw)));   // == phase-1 chain
            if (e2 < mm) { mm = e2; px = x; py = y; pz = z; }  // first min
        }
    }

    float dx = px - bx0;
    float dy = py - by0;
    float dz = pz - bz0;
    float dist = sqrtf((dx * dx + dy * dy) + dz * dz);

    float* row = bps_out + (size_t)b * IN_;
    row[k]              = dist;
    row[K_ + 3 * k + 0] = dx;
    row[K_ + 3 * k + 1] = dy;
    row[K_ + 3 * k + 2] = dz;
}

// -------------------------------------------------------------------------
// L1 GEMM (validated r13, 167.5): read-W-once, 1024 blocks (4/CU).
// partial layout [chunk][16][H1].
// -------------------------------------------------------------------------
template<int ILEN, int NCOLS>
__global__ __launch_bounds__(256) void gemm1(
    const float* __restrict__ A, const float* __restrict__ W,
    float* __restrict__ part)
{
    __shared__ float red[4][64][33];
    const int lane = (int)threadIdx.x & 63;
    const int w    = __builtin_amdgcn_readfirstlane((int)threadIdx.x >> 6);
    const int j0   = blockIdx.x * 128 + lane * 2;
    const int i0   = blockIdx.y * ILEN + w * (ILEN / 4);

    float2 acc[16];
#pragma unroll
    for (int r = 0; r < 16; ++r) acc[r] = make_float2(0.f, 0.f);

#pragma unroll 4
    for (int i = i0; i < i0 + ILEN / 4; ++i) {
        float2 wv = *(const float2*)(W + (size_t)i * NCOLS + j0);
#pragma unroll
        for (int r = 0; r < 16; ++r) {
            float a = A[(size_t)r * IN_ + i];       // wave-uniform -> s_load
            acc[r].x = __builtin_fmaf(a, wv.x, acc[r].x);
            acc[r].y = __builtin_fmaf(a, wv.y, acc[r].y);
        }
    }

#pragma unroll
    for (int r = 0; r < 16; ++r) {
        red[w][lane][2 * r]     = acc[r].x;
        red[w][lane][2 * r + 1] = acc[r].y;
    }
    __syncthreads();

    // cross-wave fold: thread (w, lane) -> batches [4w, 4w+4) x col pair lane
    float* base = part + (size_t)blockIdx.y * 16 * NCOLS + blockIdx.x * 128 + lane * 2;
    const int b0 = w * 4;
#pragma unroll
    for (int b = b0; b < b0 + 4; ++b) {
        float sx = 0.f, sy = 0.f;
#pragma unroll
        for (int ww = 0; ww < 4; ++ww) {
            sx += red[ww][lane][2 * b];
            sy += red[ww][lane][2 * b + 1];
        }
        *(float2*)(base + (size_t)b * NCOLS) = make_float2(sx, sy);
    }
}

// -------------------------------------------------------------------------
// Reduce 128 chunk-partials + bias + leaky -> h1T[col][16]  (validated r13)
// -------------------------------------------------------------------------
__global__ __launch_bounds__(256) void reduce_act1(
    const float* __restrict__ part, const float* __restrict__ bias,
    float* __restrict__ outT)
{
    const int p = blockIdx.x * 256 + (int)threadIdx.x;   // b*H1 + col
    float s = 0.0f;
#pragma unroll 8
    for (int c = 0; c < GCH; ++c) s += part[(size_t)c * (16 * H1_) + p];
    const int col = p & (H1_ - 1);
    const int b   = p >> 10;
    s += bias[col];
    s = fmaxf(s, LEAKY_SLOPE * s);
    outT[(size_t)col * 16 + b] = s;
}

// -------------------------------------------------------------------------
// L2 GEMM, split-K (validated r4/r10/r13): grid (8 colblocks x 8 kslices).
// part layout: [slice][col][16].  No bias/act (folded into gemm_last).
// -------------------------------------------------------------------------
template<int KDIM, int NCOLS>
__global__ __launch_bounds__(256) void gemm_mid(
    const float* __restrict__ AT, const float* __restrict__ W,
    float* __restrict__ part)
{
    __shared__ float red[4][64][17];
    const int lane = (int)threadIdx.x & 63;
    const int w    = __builtin_amdgcn_readfirstlane((int)threadIdx.x >> 6);
    const int cb   = blockIdx.x;
    const int s    = blockIdx.y;
    const int j    = cb * 64 + lane;
    constexpr int KS = KDIM / 8;    // 128 i per slice
    constexpr int KW = KS / 4;      // 32 i per wave
    const int i0 = s * KS + w * KW;

    float acc[16];
#pragma unroll
    for (int r = 0; r < 16; ++r) acc[r] = 0.0f;

#pragma unroll 4
    for (int i = i0; i < i0 + KW; ++i) {
        float wv = W[(size_t)i * NCOLS + j];
        const float4* Ar = (const float4*)(AT + (size_t)i * 16);
        float4 q0 = Ar[0], q1 = Ar[1], q2 = Ar[2], q3 = Ar[3];
        acc[0]  = __builtin_fmaf(q0.x, wv, acc[0]);
        acc[1]  = __builtin_fmaf(q0.y, wv, acc[1]);
        acc[2]  = __builtin_fmaf(q0.z, wv, acc[2]);
        acc[3]  = __builtin_fmaf(q0.w, wv, acc[3]);
        acc[4]  = __builtin_fmaf(q1.x, wv, acc[4]);
        acc[5]  = __builtin_fmaf(q1.y, wv, acc[5]);
        acc[6]  = __builtin_fmaf(q1.z, wv, acc[6]);
        acc[7]  = __builtin_fmaf(q1.w, wv, acc[7]);
        acc[8]  = __builtin_fmaf(q2.x, wv, acc[8]);
        acc[9]  = __builtin_fmaf(q2.y, wv, acc[9]);
        acc[10] = __builtin_fmaf(q2.z, wv, acc[10]);
        acc[11] = __builtin_fmaf(q2.w, wv, acc[11]);
        acc[12] = __builtin_fmaf(q3.x, wv, acc[12]);
        acc[13] = __builtin_fmaf(q3.y, wv, acc[13]);
        acc[14] = __builtin_fmaf(q3.z, wv, acc[14]);
        acc[15] = __builtin_fmaf(q3.w, wv, acc[15]);
    }

#pragma unroll
    for (int r = 0; r < 16; ++r) red[w][lane][r] = acc[r];
    __syncthreads();

#pragma unroll
    for (int q = 0; q < 4; ++q) {
        int p  = (int)threadIdx.x * 4 + q;   // col_local*16 + batch
        int cl = p >> 4;
        int bt = p & 15;
        float ssum = 0.0f;
#pragma unroll
        for (int ww = 0; ww < 4; ++ww) ssum += red[ww][cl][bt];
        part[((size_t)s * NCOLS + cb * 64 + cl) * 16 + bt] = ssum;
    }
}

// -------------------------------------------------------------------------
// L3 GEMM, split-K, layer-2 epilogue folded into A-prep (validated r13).
// grid (4 colblocks x 8 kslices) = 32 blocks.
// -------------------------------------------------------------------------
template<int KDIM, int NCOLS>
__global__ __launch_bounds__(256) void gemm_last(
    const float* __restrict__ h2part, const float* __restrict__ b2,
    const float* __restrict__ W, float* __restrict__ part)
{
    __shared__ float aT[64][20];
    __shared__ float red[4][64][17];
    const int lane = (int)threadIdx.x & 63;
    const int w    = __builtin_amdgcn_readfirstlane((int)threadIdx.x >> 6);
    const int cb   = blockIdx.x;
    const int s    = blockIdx.y;
    constexpr int KS = KDIM / 8;        // 64 i per slice

    {
        const int il  = (int)threadIdx.x >> 2;
        const int btq = ((int)threadIdx.x & 3) * 4;
        const int i   = s * KS + il;
        float4 sum = make_float4(0.f, 0.f, 0.f, 0.f);
#pragma unroll
        for (int sl = 0; sl < 8; ++sl) {
            const float4 v = *(const float4*)(h2part +
                ((size_t)sl * H2_ + i) * 16 + btq);
            sum.x += v.x; sum.y += v.y; sum.z += v.z; sum.w += v.w;
        }
        const float bb = b2[i];
        sum.x += bb; sum.y += bb; sum.z += bb; sum.w += bb;
        sum.x = fmaxf(sum.x, LEAKY_SLOPE * sum.x);
        sum.y = fmaxf(sum.y, LEAKY_SLOPE * sum.y);
        sum.z = fmaxf(sum.z, LEAKY_SLOPE * sum.z);
        sum.w = fmaxf(sum.w, LEAKY_SLOPE * sum.w);
        *(float4*)&aT[il][btq] = sum;
    }
    __syncthreads();

    const int j  = cb * 64 + lane;
    const int i0 = w * 16;
    float acc[16];
#pragma unroll
    for (int r = 0; r < 16; ++r) acc[r] = 0.0f;

#pragma unroll 4
    for (int il = i0; il < i0 + 16; ++il) {
        float wv = W[((size_t)(s * KS + il)) * NCOLS + j];
        float4 q0 = *(const float4*)&aT[il][0];
        float4 q1 = *(const float4*)&aT[il][4];
        float4 q2 = *(const float4*)&aT[il][8];
        float4 q3 = *(const float4*)&aT[il][12];
        acc[0]  = __builtin_fmaf(q0.x, wv, acc[0]);
        acc[1]  = __builtin_fmaf(q0.y, wv, acc[1]);
        acc[2]  = __builtin_fmaf(q0.z, wv, acc[2]);
        acc[3]  = __builtin_fmaf(q0.w, wv, acc[3]);
        acc[4]  = __builtin_fmaf(q1.x, wv, acc[4]);
        acc[5]  = __builtin_fmaf(q1.y, wv, acc[5]);
        acc[6]  = __builtin_fmaf(q1.z, wv, acc[6]);
        acc[7]  = __builtin_fmaf(q1.w, wv, acc[7]);
        acc[8]  = __builtin_fmaf(q2.x, wv, acc[8]);
        acc[9]  = __builtin_fmaf(q2.y, wv, acc[9]);
        acc[10] = __builtin_fmaf(q2.z, wv, acc[10]);
        acc[11] = __builtin_fmaf(q2.w, wv, acc[11]);
        acc[12] = __builtin_fmaf(q3.x, wv, acc[12]);
        acc[13] = __builtin_fmaf(q3.y, wv, acc[13]);
        acc[14] = __builtin_fmaf(q3.z, wv, acc[14]);
        acc[15] = __builtin_fmaf(q3.w, wv, acc[15]);
    }

#pragma unroll
    for (int r = 0; r < 16; ++r) red[w][lane][r] = acc[r];
    __syncthreads();

#pragma unroll
    for (int q = 0; q < 4; ++q) {
        int p  = (int)threadIdx.x * 4 + q;
        int cl = p >> 4;
        int bt = p & 15;
        float ssum = 0.0f;
#pragma unroll
        for (int ww = 0; ww < 4; ++ww) ssum += red[ww][cl][bt];
        part[((size_t)s * NCOLS + cb * 64 + cl) * 16 + bt] = ssum;
    }
}

// -------------------------------------------------------------------------
// Final: fold 8 h3 k-slices + b3 -> gfeat [16][256]  (validated r13)
// -------------------------------------------------------------------------
__global__ __launch_bounds__(256) void out_final(
    const float* __restrict__ h3part, const float* __restrict__ b3,
    float* __restrict__ out)
{
    const int t   = blockIdx.x * 256 + (int)threadIdx.x;  // 0..4095
    const int col = t >> 4;
    const int bt  = t & 15;
    float s = b3[col];
#pragma unroll
    for (int sl = 0; sl < 8; ++sl)
        s += h3part[((size_t)sl * OUT_ + col) * 16 + bt];
    out[(size_t)bt * OUT_ + col] = s;
}

// -------------------------------------------------------------------------
extern "C" void kernel_launch(void* const* d_in, const int* in_sizes, int n_in,
                              void* d_out, int out_size, void* d_ws, size_t ws_size,
                              hipStream_t stream)
{
    const float* pc    = (const float*)d_in[0];
    const float* basis = (const float*)d_in[1];
    const float* W1    = (const float*)d_in[2];
    const float* b1    = (const float*)d_in[3];
    const float* W2    = (const float*)d_in[4];
    const float* b2    = (const float*)d_in[5];
    const float* W3    = (const float*)d_in[6];
    const float* b3    = (const float*)d_in[7];

    float* out   = (float*)d_out;
    float* gfeat = out;                 // [16][256]
    float* bps   = out + B_ * OUT_;     // [16][16384]

    char* ws = (char*)d_ws;
    float* chunkminf = (float*)ws;                                   // 16 MB
    float* partial = (float*)(ws + (size_t)16 * 1024 * 1024);        // 8 MB [128][16][H1]
    float* h1T     = (float*)(ws + (size_t)24 * 1024 * 1024);        // 64 KB
    float* h2part  = (float*)(ws + (size_t)24 * 1024 * 1024 + 64 * 1024);   // 256 KB
    float* h3part  = (float*)(ws + (size_t)24 * 1024 * 1024 + 320 * 1024);  // 128 KB

    // 1) phase-1 min-only per chunk (4 VALU/pair, no atomics, no index)
    enc_partial<<<dim3(K_ / KTB, B_, NCH), 256, 0, stream>>>(pc, basis, chunkminf);
    // 2) fold 64 chunk-mins + rescan winning chunk + write bps feature
    enc_reduce_finish<<<(B_ * K_) / 256, 256, 0, stream>>>(pc, basis, chunkminf, bps);
    // 3) L1 GEMM [16,16384]@[16384,1024]; 1024 blocks (4/CU)
    gemm1<128, H1_><<<dim3(8, GCH), 256, 0, stream>>>(bps, W1, partial);
    // 4) reduce 128 partials + bias + leaky -> h1T
    reduce_act1<<<(H1_ * 16) / 256, 256, 0, stream>>>(partial, b1, h1T);
    // 5) L2 split-K GEMM [16,1024]@[1024,512] -> h2part[8][512][16]
    gemm_mid<1024, H2_><<<dim3(8, 8), 256, 0, stream>>>(h1T, W2, h2part);
    // 6) L3 split-K GEMM (layer-2 reduce+act folded into A-prep) -> h3part
    gemm_last<512, OUT_><<<dim3(4, 8), 256, 0, stream>>>(h2part, b2, W3, h3part);
    // 7) fold slices + b3 -> final output
    out_final<<<16, 256, 0, stream>>>(h3part, b3, gfeat);
}